// Round 3
// 937.021 us; speedup vs baseline: 1.2098x; 1.2098x over previous
//
#include <hip/hip_runtime.h>
#include <cstdio>
#include <cstdint>

typedef __bf16 bf16;
typedef __bf16 bf16x8 __attribute__((ext_vector_type(8)));
typedef __bf16 bf16x4 __attribute__((ext_vector_type(4)));
typedef float  f32x4  __attribute__((ext_vector_type(4)));

#define SEQ  2048
#define DIMM 2048
#define ROWS 4096   // B*S
#define EPSF 1e-5f

// ---- async global->LDS, 16B per lane (dest must be waveuniform + lane*16) ----
__device__ __forceinline__ void g2l16(const void* g, void* l) {
  __builtin_amdgcn_global_load_lds((__attribute__((address_space(1))) void*)g,
                                   (__attribute__((address_space(3))) void*)l,
                                   16, 0, 0);
}

// ============================================================================
// gemm256: 256x256 tile, BK=64, 512 threads = 8 waves (2M x 4N), 4 phases per
// K-tile (16 MFMA each), counted vmcnt (never 0 in the main loop), T2
// XOR-swizzled LDS (linear dest + pre-swizzled global source + swizzled
// ds_read), T5 setprio around MFMA clusters. Rule-18 sched_barrier(0) after
// every inline-asm waitcnt that guards MFMA register operands.
// C[M,N] = A[M,K] @ Bw[N,K]^T (+bias, + mode epilogue)
// MODE 0: bf16 out = acc + bias0
// MODE 5: bf16 out, tri-bias (QKV fused)
// MODE 6: bf16 out, bi-bias  (W1W2 fused)
// ============================================================================
template<int MODE>
__global__ __launch_bounds__(512, 2)
void gemm256(const bf16* __restrict__ A, int ldA,
             const bf16* __restrict__ Bw, int K,
             const float* __restrict__ bias0,
             const float* __restrict__ bias1,
             const float* __restrict__ bias2,
             void* __restrict__ Cout, int ldC)
{
  // [dbuf][A/B][256 rows x 64 bf16]  = 128 KiB total
  __shared__ bf16 lds[2][2][256 * 64];
  const int tid  = threadIdx.x;
  const int lane = tid & 63;
  const int wave = tid >> 6;
  const int wm = wave >> 2, wn = wave & 3;   // 2 x 4 wave grid
  const int lm = lane & 15, lq = lane >> 4;
  const long row0 = (long)blockIdx.y * 256;
  const long col0 = (long)blockIdx.x * 256;
  const bf16* Ab = A  + row0 * ldA;
  const bf16* Bb = Bw + col0 * (long)K;
  const int NT = K >> 6;                     // K-tiles of 64

  // Staging: per matrix a K-tile is 256 rows x 128 B = 2048 x 16B chunks =
  // 4 slots x 512 chunks. Thread handles chunk tid of each slot:
  // row = s*64 + (tid>>3), chunk-col = tid&7. Global source chunk-col is
  // XOR-swizzled by (row&7) so the LINEAR LDS write yields the swizzled
  // layout; ds_read applies the same XOR (involution).
  const int srow = tid >> 3;
  const int scol = (tid & 7) ^ (srow & 7);
  const long sAoff = (long)srow * ldA + scol * 8;
  const long sBoff = (long)srow * (long)K + scol * 8;
  const int  ldst  = tid * 8;                // element offset inside a slot

#define STAGE_A(buf, s, k0) \
  g2l16(Ab + (long)(s) * 64 * ldA + sAoff + (k0), &lds[buf][0][(s) * 4096 + ldst])
#define STAGE_B(buf, s, k0) \
  g2l16(Bb + (long)(s) * 64 * (long)K + sBoff + (k0), &lds[buf][1][(s) * 4096 + ldst])
// swizzled fragment read: 16B at row r, chunk-col c16 (0..7), XOR (r&7)
#define LD_A(buf, r, c16) (*(const bf16x8*)(&lds[buf][0][(r) * 64 + (((c16) ^ ((r) & 7)) * 8)]))
#define LD_B(buf, r, c16) (*(const bf16x8*)(&lds[buf][1][(r) * 64 + (((c16) ^ ((r) & 7)) * 8)]))

  f32x4 acc[8][4] = {};

  // ---- prologue: tile0 fully into buf0; tile1 A-rows 0..127 into buf1 ----
  STAGE_A(0, 0, 0); STAGE_A(0, 1, 0); STAGE_A(0, 2, 0); STAGE_A(0, 3, 0);
  STAGE_B(0, 0, 0); STAGE_B(0, 1, 0); STAGE_B(0, 2, 0); STAGE_B(0, 3, 0);
  {
    const long k1 = (NT > 1) ? 64 : 0;
    STAGE_A(1, 0, k1); STAGE_A(1, 1, k1);
  }
  asm volatile("s_waitcnt vmcnt(2)" ::: "memory");   // tile0 landed
  __builtin_amdgcn_sched_barrier(0);
  __builtin_amdgcn_s_barrier();

  for (int kt = 0; kt < NT; ++kt) {
    const int cur = kt & 1, nxt = cur ^ 1;
    const long kn1 = (long)((kt + 1 < NT) ? kt + 1 : NT - 1) * 64;  // clamped: keeps
    const long kn2 = (long)((kt + 2 < NT) ? kt + 2 : NT - 1) * 64;  // vmcnt counts uniform
    bf16x8 a0[4][2], a1[4][2], b0[2][2], b1[2][2];

    // ---- phase 0: quad (m0,n0). read A-h0 + B-h0; stage A rows128..255 of kt+1
#pragma unroll
    for (int mi = 0; mi < 4; ++mi) {
      const int r = wm * 128 + mi * 16 + lm;
#pragma unroll
      for (int ks = 0; ks < 2; ++ks) a0[mi][ks] = LD_A(cur, r, ks * 4 + lq);
    }
#pragma unroll
    for (int ni = 0; ni < 2; ++ni) {
      const int r = wn * 64 + ni * 16 + lm;
#pragma unroll
      for (int ks = 0; ks < 2; ++ks) b0[ni][ks] = LD_B(cur, r, ks * 4 + lq);
    }
    STAGE_A(nxt, 2, kn1); STAGE_A(nxt, 3, kn1);
    __builtin_amdgcn_s_barrier();
    asm volatile("s_waitcnt lgkmcnt(0)" ::: "memory");
    __builtin_amdgcn_sched_barrier(0);          // rule 18: pin MFMA below wait
    __builtin_amdgcn_s_setprio(1);
#pragma unroll
    for (int ks = 0; ks < 2; ++ks)
#pragma unroll
      for (int mi = 0; mi < 4; ++mi)
#pragma unroll
        for (int ni = 0; ni < 2; ++ni)
          acc[mi][ni] = __builtin_amdgcn_mfma_f32_16x16x32_bf16(a0[mi][ks], b0[ni][ks], acc[mi][ni], 0, 0, 0);
    __builtin_amdgcn_s_setprio(0);
    __builtin_amdgcn_s_barrier();

    // ---- phase 1: quad (m0,n1). read B-h1; stage B rows0..127 of kt+1
#pragma unroll
    for (int ni = 0; ni < 2; ++ni) {
      const int r = wn * 64 + 32 + ni * 16 + lm;
#pragma unroll
      for (int ks = 0; ks < 2; ++ks) b1[ni][ks] = LD_B(cur, r, ks * 4 + lq);
    }
    STAGE_B(nxt, 0, kn1); STAGE_B(nxt, 1, kn1);
    __builtin_amdgcn_s_barrier();
    asm volatile("s_waitcnt lgkmcnt(0)" ::: "memory");
    __builtin_amdgcn_sched_barrier(0);
    __builtin_amdgcn_s_setprio(1);
#pragma unroll
    for (int ks = 0; ks < 2; ++ks)
#pragma unroll
      for (int mi = 0; mi < 4; ++mi)
#pragma unroll
        for (int ni = 0; ni < 2; ++ni)
          acc[mi][2 + ni] = __builtin_amdgcn_mfma_f32_16x16x32_bf16(a0[mi][ks], b1[ni][ks], acc[mi][2 + ni], 0, 0, 0);
    __builtin_amdgcn_s_setprio(0);
    __builtin_amdgcn_s_barrier();

    // ---- phase 2: quad (m1,n0). read A-h1; stage B rows128..255 of kt+1
#pragma unroll
    for (int mi = 0; mi < 4; ++mi) {
      const int r = wm * 128 + 64 + mi * 16 + lm;
#pragma unroll
      for (int ks = 0; ks < 2; ++ks) a1[mi][ks] = LD_A(cur, r, ks * 4 + lq);
    }
    STAGE_B(nxt, 2, kn1); STAGE_B(nxt, 3, kn1);
    __builtin_amdgcn_s_barrier();
    asm volatile("s_waitcnt lgkmcnt(0)" ::: "memory");
    __builtin_amdgcn_sched_barrier(0);
    __builtin_amdgcn_s_setprio(1);
#pragma unroll
    for (int ks = 0; ks < 2; ++ks)
#pragma unroll
      for (int mi = 0; mi < 4; ++mi)
#pragma unroll
        for (int ni = 0; ni < 2; ++ni)
          acc[4 + mi][ni] = __builtin_amdgcn_mfma_f32_16x16x32_bf16(a1[mi][ks], b0[ni][ks], acc[4 + mi][ni], 0, 0, 0);
    __builtin_amdgcn_s_setprio(0);
    __builtin_amdgcn_s_barrier();

    // ---- phase 3: quad (m1,n1). stage A rows0..127 of kt+2 into cur buffer
    // (its reads finished at phase 2, whose end-barrier follows every wave's
    // lgkmcnt(0)). Counted wait: the 2 loads just issued may stay in flight;
    // everything older (all of tile kt+1) must be done.
    STAGE_A(cur, 0, kn2); STAGE_A(cur, 1, kn2);
    asm volatile("s_waitcnt vmcnt(2)" ::: "memory");
    __builtin_amdgcn_sched_barrier(0);
    __builtin_amdgcn_s_barrier();
    __builtin_amdgcn_s_setprio(1);
#pragma unroll
    for (int ks = 0; ks < 2; ++ks)
#pragma unroll
      for (int mi = 0; mi < 4; ++mi)
#pragma unroll
        for (int ni = 0; ni < 2; ++ni)
          acc[4 + mi][2 + ni] = __builtin_amdgcn_mfma_f32_16x16x32_bf16(a1[mi][ks], b1[ni][ks], acc[4 + mi][2 + ni], 0, 0, 0);
    __builtin_amdgcn_s_setprio(0);
    __builtin_amdgcn_s_barrier();
  }

  // epilogue: C/D layout col=lane&15, row=(lane>>4)*4+reg
#pragma unroll
  for (int nj = 0; nj < 4; ++nj) {
    const long col = col0 + wn * 64 + nj * 16 + lm;
    float bv;
    if (MODE == 5)
      bv = (col < 2048) ? bias0[col] : (col < 4096 ? bias1[col - 2048] : bias2[col - 4096]);
    else if (MODE == 6)
      bv = (col < 2048) ? bias0[col] : bias1[col - 2048];
    else
      bv = bias0[col];
#pragma unroll
    for (int fi = 0; fi < 8; ++fi) {
#pragma unroll
      for (int r = 0; r < 4; ++r) {
        const long row = row0 + wm * 128 + fi * 16 + lq * 4 + r;
        ((bf16*)Cout)[row * ldC + col] = (bf16)(acc[fi][nj][r] + bv);
      }
    }
  }
#undef STAGE_A
#undef STAGE_B
#undef LD_A
#undef LD_B
}

// ============================================================================
// old 128x128 GEMM — kept for the O-projection (M=4096,N=2048: at 256^2 tiles
// the grid would be 128 blocks = half the GPU idle). MODE 1 only:
// f32 out = resid + acc + bias0 (in-place on resid allowed)
// ============================================================================
template<int MODE>
__global__ __launch_bounds__(256)
void gemm_bt(const bf16* __restrict__ A, int ldA,
             const bf16* __restrict__ Bw, int K,
             const float* __restrict__ bias0,
             void* Cout, int ldC,
             const float* resid)
{
  __shared__ bf16 sA[128 * 32];
  __shared__ bf16 sB[128 * 32];
  const int tid  = threadIdx.x;
  const int lane = tid & 63;
  const int wave = tid >> 6;
  const int wm = wave >> 1, wn = wave & 1;
  const long row0 = (long)blockIdx.y * 128;
  const long col0 = (long)blockIdx.x * 128;

  const bf16* Ab = A  + row0 * ldA;
  const bf16* Bb = Bw + col0 * (long)K;

  f32x4 acc[4][4] = {};

  const int c0 = tid,        c1 = tid + 256;
  const int r0 = c0 >> 2,    cc0 = (c0 & 3) * 8;
  const int r1 = c1 >> 2,    cc1 = (c1 & 3) * 8;

  for (int k0 = 0; k0 < K; k0 += 32) {
    g2l16(Ab + (long)r0 * ldA + k0 + cc0, sA + c0 * 8);
    g2l16(Ab + (long)r1 * ldA + k0 + cc1, sA + c1 * 8);
    g2l16(Bb + (long)r0 * K   + k0 + cc0, sB + c0 * 8);
    g2l16(Bb + (long)r1 * K   + k0 + cc1, sB + c1 * 8);
    __syncthreads();
    const int lm = lane & 15, lq = lane >> 4;
    bf16x8 af[4], bfr[4];
#pragma unroll
    for (int mi = 0; mi < 4; ++mi)
      af[mi] = *(const bf16x8*)(sA + (wm * 64 + mi * 16 + lm) * 32 + lq * 8);
#pragma unroll
    for (int ni = 0; ni < 4; ++ni)
      bfr[ni] = *(const bf16x8*)(sB + (wn * 64 + ni * 16 + lm) * 32 + lq * 8);
#pragma unroll
    for (int mi = 0; mi < 4; ++mi)
#pragma unroll
      for (int ni = 0; ni < 4; ++ni)
        acc[mi][ni] = __builtin_amdgcn_mfma_f32_16x16x32_bf16(af[mi], bfr[ni], acc[mi][ni], 0, 0, 0);
    __syncthreads();
  }

  const int lm = lane & 15, lq = lane >> 4;
#pragma unroll
  for (int ni = 0; ni < 4; ++ni) {
    const long col = col0 + wn * 64 + ni * 16 + lm;
    const float bv = bias0[col];
#pragma unroll
    for (int mi = 0; mi < 4; ++mi) {
#pragma unroll
      for (int r = 0; r < 4; ++r) {
        const long row = row0 + wm * 64 + mi * 16 + lq * 4 + r;
        const long idx = row * ldC + col;
        ((float*)Cout)[idx] = resid[idx] + acc[mi][ni][r] + bv;
      }
    }
  }
}

// ============================================================================
// fused (optional additive-rotary) + RMSNorm
// ============================================================================
__global__ __launch_bounds__(256)
void rms_rot(const float* __restrict__ xin,
             const float* __restrict__ scale,
             float* __restrict__ xr_out,
             bf16* __restrict__ h_out,
             int do_rot)
{
  const int row = blockIdx.x, tid = threadIdx.x;
  const float s = (float)(row & (SEQ - 1));
  const float4* xrow = (const float4*)(xin + (long)row * DIMM);
  float4 v[2];
  float ss = 0.f;
#pragma unroll
  for (int i = 0; i < 2; ++i) {
    const int j4 = tid + i * 256;
    float4 xv = xrow[j4];
    if (do_rot) {
      float* xp = (float*)&xv;
#pragma unroll
      for (int l = 0; l < 4; ++l) {
        const int idx = (j4 * 4 + l) & 1023;
        xp[l] += s * exp2f((float)idx * -0.0129762816206537569f);
      }
    }
    v[i] = xv;
    ss += xv.x * xv.x + xv.y * xv.y + xv.z * xv.z + xv.w * xv.w;
    if (xr_out) ((float4*)(xr_out + (long)row * DIMM))[j4] = xv;
  }
#pragma unroll
  for (int off = 32; off > 0; off >>= 1) ss += __shfl_down(ss, off, 64);
  __shared__ float red[4];
  if ((tid & 63) == 0) red[tid >> 6] = ss;
  __syncthreads();
  const float rn = rsqrtf(red[0] + red[1] + red[2] + red[3] + EPSF);
  bf16* hrow = h_out + (long)row * DIMM;
#pragma unroll
  for (int i = 0; i < 2; ++i) {
    const int j4 = tid + i * 256;
    const float4 xv = v[i];
    const float4 s4 = ((const float4*)scale)[j4];
    bf16x4 o;
    o[0] = (bf16)(s4.x * xv.x * rn);
    o[1] = (bf16)(s4.y * xv.y * rn);
    o[2] = (bf16)(s4.z * xv.z * rn);
    o[3] = (bf16)(s4.w * xv.w * rn);
    *(bf16x4*)(hrow + j4 * 4) = o;
  }
}

// ============================================================================
// per-position attention over HEADS
// ============================================================================
__global__ __launch_bounds__(256)
void attn_kernel(const bf16* QKV, bf16* CTX)
{
  __shared__ float qs[32 * 68];
  __shared__ float ks[32 * 68];
  __shared__ float vs[2048];
  __shared__ float sc[32 * 33];
  const int p = blockIdx.x, tid = threadIdx.x;
  const bf16* base = QKV + (long)p * 6144;
  {
    const bf16x8 q8 = *(const bf16x8*)(base + tid * 8);
    const bf16x8 k8 = *(const bf16x8*)(base + 2048 + tid * 8);
    const bf16x8 v8 = *(const bf16x8*)(base + 4096 + tid * 8);
    const int hi = tid >> 3, d0 = (tid & 7) * 8;
#pragma unroll
    for (int l = 0; l < 8; ++l) {
      qs[hi * 68 + d0 + l] = (float)q8[l];
      ks[hi * 68 + d0 + l] = (float)k8[l];
      vs[hi * 64 + d0 + l] = (float)v8[l];
    }
  }
  __syncthreads();
  {
    const int qi = tid >> 3, ku = tid & 7;
    float a[4] = {0.f, 0.f, 0.f, 0.f};
#pragma unroll
    for (int d = 0; d < 64; d += 4) {
      const float4 qv = *(const float4*)&qs[qi * 68 + d];
#pragma unroll
      for (int c = 0; c < 4; ++c) {
        const float4 kv = *(const float4*)&ks[(ku + 8 * c) * 68 + d];
        a[c] += qv.x * kv.x + qv.y * kv.y + qv.z * kv.z + qv.w * kv.w;
      }
    }
#pragma unroll
    for (int c = 0; c < 4; ++c) sc[qi * 33 + ku + 8 * c] = a[c] * 0.125f;
  }
  __syncthreads();
  if (tid < 32) {
    float mx = -1e30f;
#pragma unroll
    for (int k = 0; k < 32; ++k) mx = fmaxf(mx, sc[tid * 33 + k]);
    float e[32], sum = 0.f;
#pragma unroll
    for (int k = 0; k < 32; ++k) { e[k] = __expf(sc[tid * 33 + k] - mx); sum += e[k]; }
    const float inv = 1.f / sum;
#pragma unroll
    for (int k = 0; k < 32; ++k) sc[tid * 33 + k] = e[k] * inv;
  }
  __syncthreads();
  {
    const int q = tid >> 3, d0 = (tid & 7) * 8;
    float a[8] = {};
#pragma unroll
    for (int k = 0; k < 32; ++k) {
      const float w = sc[q * 33 + k];
      const float4 v0 = *(const float4*)&vs[k * 64 + d0];
      const float4 v1 = *(const float4*)&vs[k * 64 + d0 + 4];
      a[0] += w * v0.x; a[1] += w * v0.y; a[2] += w * v0.z; a[3] += w * v0.w;
      a[4] += w * v1.x; a[5] += w * v1.y; a[6] += w * v1.z; a[7] += w * v1.w;
    }
    bf16x8 o;
#pragma unroll
    for (int l = 0; l < 8; ++l) o[l] = (bf16)a[l];
    *(bf16x8*)(CTX + (long)p * 6144 + tid * 8) = o;
  }
}

// ============================================================================
// swiglu combine
// ============================================================================
__global__ __launch_bounds__(256)
void swiglu_combine(const bf16* __restrict__ G12, const float* __restrict__ R,
                    float* __restrict__ out)
{
  const long idx = ((long)blockIdx.x * 256 + threadIdx.x) * 8;
  const long row = idx >> 11, col = idx & 2047;
  const bf16x8 g1 = *(const bf16x8*)(G12 + row * 4096 + col);
  const bf16x8 g2 = *(const bf16x8*)(G12 + row * 4096 + 2048 + col);
  const float4 r0 = *(const float4*)(R + idx);
  const float4 r1 = *(const float4*)(R + idx + 4);
  float o[8];
  const float* rp0 = (const float*)&r0;
  const float* rp1 = (const float*)&r1;
#pragma unroll
  for (int l = 0; l < 8; ++l) {
    const float g  = (float)g1[l];
    const float si = g / (1.f + __expf(-g));
    const float rv = l < 4 ? rp0[l] : rp1[l - 4];
    o[l] = rv + si * (float)g2[l];
  }
  *(float4*)(out + idx)     = make_float4(o[0], o[1], o[2], o[3]);
  *(float4*)(out + idx + 4) = make_float4(o[4], o[5], o[6], o[7]);
}

// ============================================================================
// fp32 -> bf16 weight pool
// ============================================================================
__global__ __launch_bounds__(256)
void convert_weights(const float* __restrict__ wq, const float* __restrict__ wk,
                     const float* __restrict__ wv, const float* __restrict__ wo,
                     const float* __restrict__ w_in, const float* __restrict__ w1,
                     const float* __restrict__ w2, bf16* __restrict__ dst)
{
  const long i = ((long)blockIdx.x * 256 + threadIdx.x) * 4;
  const float* src; long loc;
  if (i < (1L << 24)) {
    const long seg = i >> 22;
    src = seg == 0 ? wq : seg == 1 ? wk : seg == 2 ? wv : wo;
    loc = i & ((1L << 22) - 1);
  } else {
    const long j = i - (1L << 24);
    const long seg = j >> 24;
    src = seg == 0 ? w_in : seg == 1 ? w1 : w2;
    loc = j & ((1L << 24) - 1);
  }
  const float4 f = *(const float4*)(src + loc);
  bf16x4 o;
  o[0] = (bf16)f.x; o[1] = (bf16)f.y; o[2] = (bf16)f.z; o[3] = (bf16)f.w;
  *(bf16x4*)(dst + i) = o;
}

extern "C" void kernel_launch(void* const* d_in, const int* in_sizes, int n_in,
                              void* d_out, int out_size, void* d_ws, size_t ws_size,
                              hipStream_t stream)
{
  const float* x      = (const float*)d_in[0];
  const float* wq     = (const float*)d_in[1];
  const float* bq     = (const float*)d_in[2];
  const float* wk     = (const float*)d_in[3];
  const float* bk     = (const float*)d_in[4];
  const float* wv     = (const float*)d_in[5];
  const float* bv     = (const float*)d_in[6];
  const float* wo     = (const float*)d_in[7];
  const float* bo     = (const float*)d_in[8];
  const float* scale1 = (const float*)d_in[9];
  const float* scale2 = (const float*)d_in[10];
  const float* w_in   = (const float*)d_in[11];
  const float* b_in   = (const float*)d_in[12];
  const float* w1     = (const float*)d_in[13];
  const float* b1     = (const float*)d_in[14];
  const float* w2     = (const float*)d_in[15];
  const float* b2     = (const float*)d_in[16];

  char* ws = (char*)d_ws;
  bf16*  WB  = (bf16*)ws;                      // 134217728 B: bf16 weight pool
  float* R   = (float*)(ws + 134217728);       //  33554432 B: fp32 residual
  bf16*  H   = (bf16*) (ws + 167772160);       //  16777216 B: bf16 normed acts
  bf16*  QKV = (bf16*) (ws + 184549376);       //  48 MB region (phase 1)
  bf16*  HID = (bf16*) (ws + 184549376);       //  64 MB region (phase 2, aliases QKV)
  bf16*  G12 = (bf16*) (ws + 251658240);       //  33554432 B: bf16 [4096,4096] g1|g2
  if (ws_size < 285212672ULL) { fprintf(stderr, "ws too small: %zu\n", ws_size); return; }

  bf16* wqkv_b = WB;
  bf16* wo_b   = WB + 12582912;
  bf16* win_b  = WB + 16777216;
  bf16* w12_b  = WB + 33554432;

  convert_weights<<<65536, 256, 0, stream>>>(wq, wk, wv, wo, w_in, w1, w2, WB);
  // xr = x + rotary ; h1 = rmsnorm(xr, scale1)
  rms_rot<<<ROWS, 256, 0, stream>>>(x, scale1, R, H, 1);
  // fused QKV: [4096,6144]  (256^2 tiles: 24 x 16 = 384 blocks)
  gemm256<5><<<dim3(24, 16), 512, 0, stream>>>(H, 2048, wqkv_b, 2048, bq, bk, bv,
                                               QKV, 6144);
  // per-position head attention; ctx -> Q slot of QKV
  attn_kernel<<<ROWS, 256, 0, stream>>>(QKV, QKV);
  // x2 = xr + ctx @ wo^T + bo   (in-place on R) — small GEMM, keep 128^2 grid
  gemm_bt<1><<<dim3(16, 32), 256, 0, stream>>>(QKV, 6144, wo_b, 2048, bo, R, 2048, R);
  // h2 = rmsnorm(x2, scale2) -> H
  rms_rot<<<ROWS, 256, 0, stream>>>(R, scale2, nullptr, H, 0);
  // hidden = h2 @ w_in^T + b_in  [4096,8192]  (32 x 16 = 512 blocks)
  gemm256<0><<<dim3(32, 16), 512, 0, stream>>>(H, 2048, win_b, 2048, b_in, nullptr, nullptr,
                                               HID, 8192);
  // fused g1|g2 = hidden @ [w1|w2]^T + [b1|b2]  (16 x 16 = 256 blocks)
  gemm256<6><<<dim3(16, 16), 512, 0, stream>>>(HID, 8192, w12_b, 8192, b1, b2, nullptr,
                                               G12, 4096);
  // out = x2 + silu(g1) * g2
  swiglu_combine<<<4096, 256, 0, stream>>>(G12, R, (float*)d_out);
}

// Round 4
// 914.092 us; speedup vs baseline: 1.2401x; 1.0251x over previous
//
#include <hip/hip_runtime.h>
#include <cstdio>
#include <cstdint>

typedef __bf16 bf16;
typedef __bf16 bf16x8 __attribute__((ext_vector_type(8)));
typedef __bf16 bf16x4 __attribute__((ext_vector_type(4)));
typedef float  f32x4  __attribute__((ext_vector_type(4)));

#define SEQ  2048
#define DIMM 2048
#define ROWS 4096   // B*S
#define EPSF 1e-5f

// ---- async global->LDS, 16B per lane (dest must be waveuniform + lane*16) ----
__device__ __forceinline__ void g2l16(const void* g, void* l) {
  __builtin_amdgcn_global_load_lds((__attribute__((address_space(1))) void*)g,
                                   (__attribute__((address_space(3))) void*)l,
                                   16, 0, 0);
}

// ============================================================================
// gemm256: 256x256 tile, BK=64, 512 threads = 8 waves (2M x 4N), 4 phases per
// K-tile (16 MFMA each). Deep pipeline: ALL 8 staging loads for tile kt+2 are
// issued at phase 3 of iter kt; the per-iteration vmcnt(8) then waits only on
// tile kt+1's loads, issued a FULL iteration (4 phases, ~600+ cyc of MFMA)
// earlier — no short-fuse waits. T2 XOR-swizzled LDS (linear dest +
// pre-swizzled global source + swizzled ds_read; conflict-free, PMC-verified
// 0), T5 setprio around MFMA clusters, rule-18 sched_barrier(0) after every
// inline-asm waitcnt guarding MFMA operands.
// C[M,N] = A[M,K] @ Bw[N,K]^T (+bias, + mode epilogue)
// MODE 0: bf16 out = acc + bias0
// MODE 5: bf16 out, tri-bias (QKV fused)
// MODE 6: bf16 out, bi-bias  (W1W2 fused)
// ============================================================================
template<int MODE>
__global__ __launch_bounds__(512, 2)
void gemm256(const bf16* __restrict__ A, int ldA,
             const bf16* __restrict__ Bw, int K,
             const float* __restrict__ bias0,
             const float* __restrict__ bias1,
             const float* __restrict__ bias2,
             void* __restrict__ Cout, int ldC)
{
  // [dbuf][A/B][256 rows x 64 bf16]  = 128 KiB total
  __shared__ bf16 lds[2][2][256 * 64];
  const int tid  = threadIdx.x;
  const int lane = tid & 63;
  const int wave = tid >> 6;
  const int wm = wave >> 2, wn = wave & 3;   // 2 x 4 wave grid
  const int lm = lane & 15, lq = lane >> 4;
  const long row0 = (long)blockIdx.y * 256;
  const long col0 = (long)blockIdx.x * 256;
  const bf16* Ab = A  + row0 * ldA;
  const bf16* Bb = Bw + col0 * (long)K;
  const int NT = K >> 6;                     // K-tiles of 64

  // Staging: per matrix a K-tile is 256 rows x 128 B = 2048 x 16B chunks =
  // 4 slots x 512 chunks. Thread handles chunk tid of each slot:
  // row = s*64 + (tid>>3), chunk-col = tid&7. Global source chunk-col is
  // XOR-swizzled by (row&7) so the LINEAR LDS write yields the swizzled
  // layout; ds_read applies the same XOR (involution).
  const int srow = tid >> 3;
  const int scol = (tid & 7) ^ (srow & 7);
  const long sAoff = (long)srow * ldA + scol * 8;
  const long sBoff = (long)srow * (long)K + scol * 8;
  const int  ldst  = tid * 8;                // element offset inside a slot

#define STAGE_A(buf, s, k0) \
  g2l16(Ab + (long)(s) * 64 * ldA + sAoff + (k0), &lds[buf][0][(s) * 4096 + ldst])
#define STAGE_B(buf, s, k0) \
  g2l16(Bb + (long)(s) * 64 * (long)K + sBoff + (k0), &lds[buf][1][(s) * 4096 + ldst])
// swizzled fragment read: 16B at row r, chunk-col c16 (0..7), XOR (r&7)
#define LD_A(buf, r, c16) (*(const bf16x8*)(&lds[buf][0][(r) * 64 + (((c16) ^ ((r) & 7)) * 8)]))
#define LD_B(buf, r, c16) (*(const bf16x8*)(&lds[buf][1][(r) * 64 + (((c16) ^ ((r) & 7)) * 8)]))

  f32x4 acc[8][4] = {};

  // ---- prologue: tile0 -> buf0 (8 loads), tile1 -> buf1 (8 loads) ----
  STAGE_A(0, 0, 0); STAGE_A(0, 1, 0); STAGE_A(0, 2, 0); STAGE_A(0, 3, 0);
  STAGE_B(0, 0, 0); STAGE_B(0, 1, 0); STAGE_B(0, 2, 0); STAGE_B(0, 3, 0);
  {
    const long k1 = (NT > 1) ? 64 : 0;
    STAGE_A(1, 0, k1); STAGE_A(1, 1, k1); STAGE_A(1, 2, k1); STAGE_A(1, 3, k1);
    STAGE_B(1, 0, k1); STAGE_B(1, 1, k1); STAGE_B(1, 2, k1); STAGE_B(1, 3, k1);
  }
  asm volatile("s_waitcnt vmcnt(8)" ::: "memory");   // tile0 landed; tile1 in flight
  __builtin_amdgcn_sched_barrier(0);
  __builtin_amdgcn_s_barrier();

  for (int kt = 0; kt < NT; ++kt) {
    const int cur = kt & 1;
    const long kn2 = (long)((kt + 2 < NT) ? kt + 2 : NT - 1) * 64;  // clamped: keeps
    bf16x8 a0[4][2], a1[4][2], b0[2][2], b1[2][2];                  // vmcnt uniform

    // ---- phase 0: quad (m0,n0). ds_read A-h0 + B-h0 of tile kt ----
#pragma unroll
    for (int mi = 0; mi < 4; ++mi) {
      const int r = wm * 128 + mi * 16 + lm;
#pragma unroll
      for (int ks = 0; ks < 2; ++ks) a0[mi][ks] = LD_A(cur, r, ks * 4 + lq);
    }
#pragma unroll
    for (int ni = 0; ni < 2; ++ni) {
      const int r = wn * 64 + ni * 16 + lm;
#pragma unroll
      for (int ks = 0; ks < 2; ++ks) b0[ni][ks] = LD_B(cur, r, ks * 4 + lq);
    }
    __builtin_amdgcn_s_barrier();
    asm volatile("s_waitcnt lgkmcnt(0)" ::: "memory");
    __builtin_amdgcn_sched_barrier(0);          // rule 18: pin MFMA below wait
    __builtin_amdgcn_s_setprio(1);
#pragma unroll
    for (int ks = 0; ks < 2; ++ks)
#pragma unroll
      for (int mi = 0; mi < 4; ++mi)
#pragma unroll
        for (int ni = 0; ni < 2; ++ni)
          acc[mi][ni] = __builtin_amdgcn_mfma_f32_16x16x32_bf16(a0[mi][ks], b0[ni][ks], acc[mi][ni], 0, 0, 0);
    __builtin_amdgcn_s_setprio(0);
    __builtin_amdgcn_s_barrier();

    // ---- phase 1: quad (m0,n1). ds_read B-h1 ----
#pragma unroll
    for (int ni = 0; ni < 2; ++ni) {
      const int r = wn * 64 + 32 + ni * 16 + lm;
#pragma unroll
      for (int ks = 0; ks < 2; ++ks) b1[ni][ks] = LD_B(cur, r, ks * 4 + lq);
    }
    __builtin_amdgcn_s_barrier();
    asm volatile("s_waitcnt lgkmcnt(0)" ::: "memory");
    __builtin_amdgcn_sched_barrier(0);
    __builtin_amdgcn_s_setprio(1);
#pragma unroll
    for (int ks = 0; ks < 2; ++ks)
#pragma unroll
      for (int mi = 0; mi < 4; ++mi)
#pragma unroll
        for (int ni = 0; ni < 2; ++ni)
          acc[mi][2 + ni] = __builtin_amdgcn_mfma_f32_16x16x32_bf16(a0[mi][ks], b1[ni][ks], acc[mi][2 + ni], 0, 0, 0);
    __builtin_amdgcn_s_setprio(0);
    __builtin_amdgcn_s_barrier();

    // ---- phase 2: quad (m1,n0). ds_read A-h1 (LAST read of tile kt's LDS) ----
#pragma unroll
    for (int mi = 0; mi < 4; ++mi) {
      const int r = wm * 128 + 64 + mi * 16 + lm;
#pragma unroll
      for (int ks = 0; ks < 2; ++ks) a1[mi][ks] = LD_A(cur, r, ks * 4 + lq);
    }
    __builtin_amdgcn_s_barrier();
    asm volatile("s_waitcnt lgkmcnt(0)" ::: "memory");
    __builtin_amdgcn_sched_barrier(0);
    __builtin_amdgcn_s_setprio(1);
#pragma unroll
    for (int ks = 0; ks < 2; ++ks)
#pragma unroll
      for (int mi = 0; mi < 4; ++mi)
#pragma unroll
        for (int ni = 0; ni < 2; ++ni)
          acc[4 + mi][ni] = __builtin_amdgcn_mfma_f32_16x16x32_bf16(a1[mi][ks], b0[ni][ks], acc[4 + mi][ni], 0, 0, 0);
    __builtin_amdgcn_s_setprio(0);
    __builtin_amdgcn_s_barrier();   // after this, ALL waves done reading buf cur

    // ---- phase 3: quad (m1,n1) — no ds_read (operands from ph1/ph2).
    // Issue ALL 8 staging loads for tile kt+2 into buf cur (now free), run
    // the MFMA cluster over them, then the counted wait vmcnt(8): drains
    // tile kt+1's 8 loads (issued at phase 3 of the PREVIOUS iteration,
    // 4 phases ago) while the 8 new loads stay in flight across the barrier.
    STAGE_A(cur, 0, kn2); STAGE_A(cur, 1, kn2);
    STAGE_A(cur, 2, kn2); STAGE_A(cur, 3, kn2);
    STAGE_B(cur, 0, kn2); STAGE_B(cur, 1, kn2);
    STAGE_B(cur, 2, kn2); STAGE_B(cur, 3, kn2);
    __builtin_amdgcn_s_setprio(1);
#pragma unroll
    for (int ks = 0; ks < 2; ++ks)
#pragma unroll
      for (int mi = 0; mi < 4; ++mi)
#pragma unroll
        for (int ni = 0; ni < 2; ++ni)
          acc[4 + mi][2 + ni] = __builtin_amdgcn_mfma_f32_16x16x32_bf16(a1[mi][ks], b1[ni][ks], acc[4 + mi][2 + ni], 0, 0, 0);
    __builtin_amdgcn_s_setprio(0);
    asm volatile("s_waitcnt vmcnt(8)" ::: "memory");
    __builtin_amdgcn_sched_barrier(0);
    __builtin_amdgcn_s_barrier();   // publishes tile kt+1's LDS for phase 0
  }

  // epilogue: C/D layout col=lane&15, row=(lane>>4)*4+reg
#pragma unroll
  for (int nj = 0; nj < 4; ++nj) {
    const long col = col0 + wn * 64 + nj * 16 + lm;
    float bv;
    if (MODE == 5)
      bv = (col < 2048) ? bias0[col] : (col < 4096 ? bias1[col - 2048] : bias2[col - 4096]);
    else if (MODE == 6)
      bv = (col < 2048) ? bias0[col] : bias1[col - 2048];
    else
      bv = bias0[col];
#pragma unroll
    for (int fi = 0; fi < 8; ++fi) {
#pragma unroll
      for (int r = 0; r < 4; ++r) {
        const long row = row0 + wm * 128 + fi * 16 + lq * 4 + r;
        ((bf16*)Cout)[row * ldC + col] = (bf16)(acc[fi][nj][r] + bv);
      }
    }
  }
#undef STAGE_A
#undef STAGE_B
#undef LD_A
#undef LD_B
}

// ============================================================================
// old 128x128 GEMM — kept for the O-projection (M=4096,N=2048: at 256^2 tiles
// the grid would be 128 blocks = half the GPU idle). MODE 1 only:
// f32 out = resid + acc + bias0 (in-place on resid allowed)
// ============================================================================
template<int MODE>
__global__ __launch_bounds__(256)
void gemm_bt(const bf16* __restrict__ A, int ldA,
             const bf16* __restrict__ Bw, int K,
             const float* __restrict__ bias0,
             void* Cout, int ldC,
             const float* resid)
{
  __shared__ bf16 sA[128 * 32];
  __shared__ bf16 sB[128 * 32];
  const int tid  = threadIdx.x;
  const int lane = tid & 63;
  const int wave = tid >> 6;
  const int wm = wave >> 1, wn = wave & 1;
  const long row0 = (long)blockIdx.y * 128;
  const long col0 = (long)blockIdx.x * 128;

  const bf16* Ab = A  + row0 * ldA;
  const bf16* Bb = Bw + col0 * (long)K;

  f32x4 acc[4][4] = {};

  const int c0 = tid,        c1 = tid + 256;
  const int r0 = c0 >> 2,    cc0 = (c0 & 3) * 8;
  const int r1 = c1 >> 2,    cc1 = (c1 & 3) * 8;

  for (int k0 = 0; k0 < K; k0 += 32) {
    g2l16(Ab + (long)r0 * ldA + k0 + cc0, sA + c0 * 8);
    g2l16(Ab + (long)r1 * ldA + k0 + cc1, sA + c1 * 8);
    g2l16(Bb + (long)r0 * K   + k0 + cc0, sB + c0 * 8);
    g2l16(Bb + (long)r1 * K   + k0 + cc1, sB + c1 * 8);
    __syncthreads();
    const int lm = lane & 15, lq = lane >> 4;
    bf16x8 af[4], bfr[4];
#pragma unroll
    for (int mi = 0; mi < 4; ++mi)
      af[mi] = *(const bf16x8*)(sA + (wm * 64 + mi * 16 + lm) * 32 + lq * 8);
#pragma unroll
    for (int ni = 0; ni < 4; ++ni)
      bfr[ni] = *(const bf16x8*)(sB + (wn * 64 + ni * 16 + lm) * 32 + lq * 8);
#pragma unroll
    for (int mi = 0; mi < 4; ++mi)
#pragma unroll
      for (int ni = 0; ni < 4; ++ni)
        acc[mi][ni] = __builtin_amdgcn_mfma_f32_16x16x32_bf16(af[mi], bfr[ni], acc[mi][ni], 0, 0, 0);
    __syncthreads();
  }

  const int lm = lane & 15, lq = lane >> 4;
#pragma unroll
  for (int ni = 0; ni < 4; ++ni) {
    const long col = col0 + wn * 64 + ni * 16 + lm;
    const float bv = bias0[col];
#pragma unroll
    for (int mi = 0; mi < 4; ++mi) {
#pragma unroll
      for (int r = 0; r < 4; ++r) {
        const long row = row0 + wm * 64 + mi * 16 + lq * 4 + r;
        const long idx = row * ldC + col;
        ((float*)Cout)[idx] = resid[idx] + acc[mi][ni][r] + bv;
      }
    }
  }
}

// ============================================================================
// fused (optional additive-rotary) + RMSNorm
// ============================================================================
__global__ __launch_bounds__(256)
void rms_rot(const float* __restrict__ xin,
             const float* __restrict__ scale,
             float* __restrict__ xr_out,
             bf16* __restrict__ h_out,
             int do_rot)
{
  const int row = blockIdx.x, tid = threadIdx.x;
  const float s = (float)(row & (SEQ - 1));
  const float4* xrow = (const float4*)(xin + (long)row * DIMM);
  float4 v[2];
  float ss = 0.f;
#pragma unroll
  for (int i = 0; i < 2; ++i) {
    const int j4 = tid + i * 256;
    float4 xv = xrow[j4];
    if (do_rot) {
      float* xp = (float*)&xv;
#pragma unroll
      for (int l = 0; l < 4; ++l) {
        const int idx = (j4 * 4 + l) & 1023;
        xp[l] += s * exp2f((float)idx * -0.0129762816206537569f);
      }
    }
    v[i] = xv;
    ss += xv.x * xv.x + xv.y * xv.y + xv.z * xv.z + xv.w * xv.w;
    if (xr_out) ((float4*)(xr_out + (long)row * DIMM))[j4] = xv;
  }
#pragma unroll
  for (int off = 32; off > 0; off >>= 1) ss += __shfl_down(ss, off, 64);
  __shared__ float red[4];
  if ((tid & 63) == 0) red[tid >> 6] = ss;
  __syncthreads();
  const float rn = rsqrtf(red[0] + red[1] + red[2] + red[3] + EPSF);
  bf16* hrow = h_out + (long)row * DIMM;
#pragma unroll
  for (int i = 0; i < 2; ++i) {
    const int j4 = tid + i * 256;
    const float4 xv = v[i];
    const float4 s4 = ((const float4*)scale)[j4];
    bf16x4 o;
    o[0] = (bf16)(s4.x * xv.x * rn);
    o[1] = (bf16)(s4.y * xv.y * rn);
    o[2] = (bf16)(s4.z * xv.z * rn);
    o[3] = (bf16)(s4.w * xv.w * rn);
    *(bf16x4*)(hrow + j4 * 4) = o;
  }
}

// ============================================================================
// per-position attention over HEADS
// ============================================================================
__global__ __launch_bounds__(256)
void attn_kernel(const bf16* QKV, bf16* CTX)
{
  __shared__ float qs[32 * 68];
  __shared__ float ks[32 * 68];
  __shared__ float vs[2048];
  __shared__ float sc[32 * 33];
  const int p = blockIdx.x, tid = threadIdx.x;
  const bf16* base = QKV + (long)p * 6144;
  {
    const bf16x8 q8 = *(const bf16x8*)(base + tid * 8);
    const bf16x8 k8 = *(const bf16x8*)(base + 2048 + tid * 8);
    const bf16x8 v8 = *(const bf16x8*)(base + 4096 + tid * 8);
    const int hi = tid >> 3, d0 = (tid & 7) * 8;
#pragma unroll
    for (int l = 0; l < 8; ++l) {
      qs[hi * 68 + d0 + l] = (float)q8[l];
      ks[hi * 68 + d0 + l] = (float)k8[l];
      vs[hi * 64 + d0 + l] = (float)v8[l];
    }
  }
  __syncthreads();
  {
    const int qi = tid >> 3, ku = tid & 7;
    float a[4] = {0.f, 0.f, 0.f, 0.f};
#pragma unroll
    for (int d = 0; d < 64; d += 4) {
      const float4 qv = *(const float4*)&qs[qi * 68 + d];
#pragma unroll
      for (int c = 0; c < 4; ++c) {
        const float4 kv = *(const float4*)&ks[(ku + 8 * c) * 68 + d];
        a[c] += qv.x * kv.x + qv.y * kv.y + qv.z * kv.z + qv.w * kv.w;
      }
    }
#pragma unroll
    for (int c = 0; c < 4; ++c) sc[qi * 33 + ku + 8 * c] = a[c] * 0.125f;
  }
  __syncthreads();
  if (tid < 32) {
    float mx = -1e30f;
#pragma unroll
    for (int k = 0; k < 32; ++k) mx = fmaxf(mx, sc[tid * 33 + k]);
    float e[32], sum = 0.f;
#pragma unroll
    for (int k = 0; k < 32; ++k) { e[k] = __expf(sc[tid * 33 + k] - mx); sum += e[k]; }
    const float inv = 1.f / sum;
#pragma unroll
    for (int k = 0; k < 32; ++k) sc[tid * 33 + k] = e[k] * inv;
  }
  __syncthreads();
  {
    const int q = tid >> 3, d0 = (tid & 7) * 8;
    float a[8] = {};
#pragma unroll
    for (int k = 0; k < 32; ++k) {
      const float w = sc[q * 33 + k];
      const float4 v0 = *(const float4*)&vs[k * 64 + d0];
      const float4 v1 = *(const float4*)&vs[k * 64 + d0 + 4];
      a[0] += w * v0.x; a[1] += w * v0.y; a[2] += w * v0.z; a[3] += w * v0.w;
      a[4] += w * v1.x; a[5] += w * v1.y; a[6] += w * v1.z; a[7] += w * v1.w;
    }
    bf16x8 o;
#pragma unroll
    for (int l = 0; l < 8; ++l) o[l] = (bf16)a[l];
    *(bf16x8*)(CTX + (long)p * 6144 + tid * 8) = o;
  }
}

// ============================================================================
// swiglu combine
// ============================================================================
__global__ __launch_bounds__(256)
void swiglu_combine(const bf16* __restrict__ G12, const float* __restrict__ R,
                    float* __restrict__ out)
{
  const long idx = ((long)blockIdx.x * 256 + threadIdx.x) * 8;
  const long row = idx >> 11, col = idx & 2047;
  const bf16x8 g1 = *(const bf16x8*)(G12 + row * 4096 + col);
  const bf16x8 g2 = *(const bf16x8*)(G12 + row * 4096 + 2048 + col);
  const float4 r0 = *(const float4*)(R + idx);
  const float4 r1 = *(const float4*)(R + idx + 4);
  float o[8];
  const float* rp0 = (const float*)&r0;
  const float* rp1 = (const float*)&r1;
#pragma unroll
  for (int l = 0; l < 8; ++l) {
    const float g  = (float)g1[l];
    const float si = g / (1.f + __expf(-g));
    const float rv = l < 4 ? rp0[l] : rp1[l - 4];
    o[l] = rv + si * (float)g2[l];
  }
  *(float4*)(out + idx)     = make_float4(o[0], o[1], o[2], o[3]);
  *(float4*)(out + idx + 4) = make_float4(o[4], o[5], o[6], o[7]);
}

// ============================================================================
// fp32 -> bf16 weight pool
// ============================================================================
__global__ __launch_bounds__(256)
void convert_weights(const float* __restrict__ wq, const float* __restrict__ wk,
                     const float* __restrict__ wv, const float* __restrict__ wo,
                     const float* __restrict__ w_in, const float* __restrict__ w1,
                     const float* __restrict__ w2, bf16* __restrict__ dst)
{
  const long i = ((long)blockIdx.x * 256 + threadIdx.x) * 4;
  const float* src; long loc;
  if (i < (1L << 24)) {
    const long seg = i >> 22;
    src = seg == 0 ? wq : seg == 1 ? wk : seg == 2 ? wv : wo;
    loc = i & ((1L << 22) - 1);
  } else {
    const long j = i - (1L << 24);
    const long seg = j >> 24;
    src = seg == 0 ? w_in : seg == 1 ? w1 : w2;
    loc = j & ((1L << 24) - 1);
  }
  const float4 f = *(const float4*)(src + loc);
  bf16x4 o;
  o[0] = (bf16)f.x; o[1] = (bf16)f.y; o[2] = (bf16)f.z; o[3] = (bf16)f.w;
  *(bf16x4*)(dst + i) = o;
}

extern "C" void kernel_launch(void* const* d_in, const int* in_sizes, int n_in,
                              void* d_out, int out_size, void* d_ws, size_t ws_size,
                              hipStream_t stream)
{
  const float* x      = (const float*)d_in[0];
  const float* wq     = (const float*)d_in[1];
  const float* bq     = (const float*)d_in[2];
  const float* wk     = (const float*)d_in[3];
  const float* bk     = (const float*)d_in[4];
  const float* wv     = (const float*)d_in[5];
  const float* bv     = (const float*)d_in[6];
  const float* wo     = (const float*)d_in[7];
  const float* bo     = (const float*)d_in[8];
  const float* scale1 = (const float*)d_in[9];
  const float* scale2 = (const float*)d_in[10];
  const float* w_in   = (const float*)d_in[11];
  const float* b_in   = (const float*)d_in[12];
  const float* w1     = (const float*)d_in[13];
  const float* b1     = (const float*)d_in[14];
  const float* w2     = (const float*)d_in[15];
  const float* b2     = (const float*)d_in[16];

  char* ws = (char*)d_ws;
  bf16*  WB  = (bf16*)ws;                      // 134217728 B: bf16 weight pool
  float* R   = (float*)(ws + 134217728);       //  33554432 B: fp32 residual
  bf16*  H   = (bf16*) (ws + 167772160);       //  16777216 B: bf16 normed acts
  bf16*  QKV = (bf16*) (ws + 184549376);       //  48 MB region (phase 1)
  bf16*  HID = (bf16*) (ws + 184549376);       //  64 MB region (phase 2, aliases QKV)
  bf16*  G12 = (bf16*) (ws + 251658240);       //  33554432 B: bf16 [4096,4096] g1|g2
  if (ws_size < 285212672ULL) { fprintf(stderr, "ws too small: %zu\n", ws_size); return; }

  bf16* wqkv_b = WB;
  bf16* wo_b   = WB + 12582912;
  bf16* win_b  = WB + 16777216;
  bf16* w12_b  = WB + 33554432;

  convert_weights<<<65536, 256, 0, stream>>>(wq, wk, wv, wo, w_in, w1, w2, WB);
  // xr = x + rotary ; h1 = rmsnorm(xr, scale1)
  rms_rot<<<ROWS, 256, 0, stream>>>(x, scale1, R, H, 1);
  // fused QKV: [4096,6144]  (256^2 tiles: 24 x 16 = 384 blocks)
  gemm256<5><<<dim3(24, 16), 512, 0, stream>>>(H, 2048, wqkv_b, 2048, bq, bk, bv,
                                               QKV, 6144);
  // per-position head attention; ctx -> Q slot of QKV
  attn_kernel<<<ROWS, 256, 0, stream>>>(QKV, QKV);
  // x2 = xr + ctx @ wo^T + bo   (in-place on R) — small GEMM, keep 128^2 grid
  gemm_bt<1><<<dim3(16, 32), 256, 0, stream>>>(QKV, 6144, wo_b, 2048, bo, R, 2048, R);
  // h2 = rmsnorm(x2, scale2) -> H
  rms_rot<<<ROWS, 256, 0, stream>>>(R, scale2, nullptr, H, 0);
  // hidden = h2 @ w_in^T + b_in  [4096,8192]  (32 x 16 = 512 blocks)
  gemm256<0><<<dim3(32, 16), 512, 0, stream>>>(H, 2048, win_b, 2048, b_in, nullptr, nullptr,
                                               HID, 8192);
  // fused g1|g2 = hidden @ [w1|w2]^T + [b1|b2]  (16 x 16 = 256 blocks)
  gemm256<6><<<dim3(16, 16), 512, 0, stream>>>(HID, 8192, w12_b, 8192, b1, b2, nullptr,
                                               G12, 4096);
  // out = x2 + silu(g1) * g2
  swiglu_combine<<<4096, 256, 0, stream>>>(G12, R, (float*)d_out);
}

// Round 5
// 869.497 us; speedup vs baseline: 1.3037x; 1.0513x over previous
//
#include <hip/hip_runtime.h>
#include <cstdio>
#include <cstdint>

typedef __bf16 bf16;
typedef __bf16 bf16x8 __attribute__((ext_vector_type(8)));
typedef __bf16 bf16x4 __attribute__((ext_vector_type(4)));
typedef float  f32x4  __attribute__((ext_vector_type(4)));

#define SEQ  2048
#define DIMM 2048
#define ROWS 4096   // B*S
#define EPSF 1e-5f

// ---- async global->LDS, 16B per lane (dest must be waveuniform + lane*16) ----
__device__ __forceinline__ void g2l16(const void* g, void* l) {
  __builtin_amdgcn_global_load_lds((__attribute__((address_space(1))) void*)g,
                                   (__attribute__((address_space(3))) void*)l,
                                   16, 0, 0);
}

// ============================================================================
// gemm256: 256x256 tile, BK=64, 512 threads = 8 waves (2M x 4N), 4 phases per
// K-tile (16 MFMA each). m201-style schedule: FINE staging interleave (2
// global_load_lds per phase, never bursts) + DEEP counted waits (vmcnt(10) at
// ph1, vmcnt(8) at ph3 — every load drains 4-7 phases after issue). Slot plan
// (tile T lives in buf T&1):
//   ph0: stage A1,A3(kt+1)->nxt   ph1: stage A0,A2(kt+2)->cur
//   ph2: stage B0,B1(kt+2)->cur   ph3: stage B2,B3(kt+2)->cur
// Reads: ph0 A-h0(slots0,2)+B-h0; ph1 B-h1; ph2 A-h1(slots1,3); ph3 none.
// T2 XOR-swizzled LDS (conflict-free, PMC-verified 0), T5 setprio, rule-18
// sched_barrier(0) after every inline-asm waitcnt guarding register operands.
// C[M,N] = A[M,K] @ Bw[N,K]^T (+bias, + mode epilogue)
// MODE 0: bf16 out = acc + bias0
// MODE 5: bf16 out, tri-bias (QKV fused)
// MODE 6: bf16 out, bi-bias  (W1W2 fused)
// ============================================================================
template<int MODE>
__global__ __launch_bounds__(512, 2)
void gemm256(const bf16* __restrict__ A, int ldA,
             const bf16* __restrict__ Bw, int K,
             const float* __restrict__ bias0,
             const float* __restrict__ bias1,
             const float* __restrict__ bias2,
             void* __restrict__ Cout, int ldC)
{
  // [dbuf][A/B][256 rows x 64 bf16]  = 128 KiB total
  __shared__ bf16 lds[2][2][256 * 64];
  const int tid  = threadIdx.x;
  const int lane = tid & 63;
  const int wave = tid >> 6;
  const int wm = wave >> 2, wn = wave & 3;   // 2 x 4 wave grid
  const int lm = lane & 15, lq = lane >> 4;
  const long row0 = (long)blockIdx.y * 256;
  const long col0 = (long)blockIdx.x * 256;
  const bf16* Ab = A  + row0 * ldA;
  const bf16* Bb = Bw + col0 * (long)K;
  const int NT = K >> 6;                     // K-tiles of 64

  // Staging: per matrix a K-tile is 4 slots x (64 rows x 128 B); one g2l16
  // per thread covers a slot (512 x 16B). Global source chunk-col is
  // XOR-swizzled by (row&7) so the LINEAR LDS write yields the swizzled
  // layout; ds_read applies the same XOR (involution).
  const int srow = tid >> 3;
  const int scol = (tid & 7) ^ (srow & 7);
  const long sAoff = (long)srow * ldA + scol * 8;
  const long sBoff = (long)srow * (long)K + scol * 8;
  const int  ldst  = tid * 8;                // element offset inside a slot

#define STAGE_A(buf, s, k0) \
  g2l16(Ab + (long)(s) * 64 * ldA + sAoff + (k0), &lds[buf][0][(s) * 4096 + ldst])
#define STAGE_B(buf, s, k0) \
  g2l16(Bb + (long)(s) * 64 * (long)K + sBoff + (k0), &lds[buf][1][(s) * 4096 + ldst])
// swizzled fragment read: 16B at row r, chunk-col c16 (0..7), XOR (r&7)
#define LD_A(buf, r, c16) (*(const bf16x8*)(&lds[buf][0][(r) * 64 + (((c16) ^ ((r) & 7)) * 8)]))
#define LD_B(buf, r, c16) (*(const bf16x8*)(&lds[buf][1][(r) * 64 + (((c16) ^ ((r) & 7)) * 8)]))

  f32x4 acc[8][4] = {};

  // ---- prologue: tile0 full (8 loads) -> buf0; tile1's A0,A2 + B0..B3
  // (6 loads, the slots iter -1 phases 1-3 would have issued) -> buf1.
  STAGE_A(0, 0, 0); STAGE_A(0, 1, 0); STAGE_A(0, 2, 0); STAGE_A(0, 3, 0);
  STAGE_B(0, 0, 0); STAGE_B(0, 1, 0); STAGE_B(0, 2, 0); STAGE_B(0, 3, 0);
  {
    const long k1 = (NT > 1) ? 64 : 0;
    STAGE_A(1, 0, k1); STAGE_A(1, 2, k1);
    STAGE_B(1, 0, k1); STAGE_B(1, 1, k1); STAGE_B(1, 2, k1); STAGE_B(1, 3, k1);
  }
  asm volatile("s_waitcnt vmcnt(6)" ::: "memory");   // tile0 landed; 6 in flight
  __builtin_amdgcn_sched_barrier(0);
  __builtin_amdgcn_s_barrier();

  for (int kt = 0; kt < NT; ++kt) {
    const int cur = kt & 1, nxt = cur ^ 1;
    const long kn1 = (long)((kt + 1 < NT) ? kt + 1 : NT - 1) * 64;  // clamped:
    const long kn2 = (long)((kt + 2 < NT) ? kt + 2 : NT - 1) * 64;  // uniform vmcnt
    bf16x8 a0[4][2], a1[4][2], b0[2][2], b1[2][2];

    // ---- phase 0: quad (m0,n0). ds_read A-h0 (slots 0,2) + B-h0.
    //      stage A1,A3 of tile kt+1 -> nxt (free since iter kt-1 ph2).
#pragma unroll
    for (int mi = 0; mi < 4; ++mi) {
      const int r = wm * 128 + mi * 16 + lm;
#pragma unroll
      for (int ks = 0; ks < 2; ++ks) a0[mi][ks] = LD_A(cur, r, ks * 4 + lq);
    }
#pragma unroll
    for (int ni = 0; ni < 2; ++ni) {
      const int r = wn * 64 + ni * 16 + lm;
#pragma unroll
      for (int ks = 0; ks < 2; ++ks) b0[ni][ks] = LD_B(cur, r, ks * 4 + lq);
    }
    STAGE_A(nxt, 1, kn1); STAGE_A(nxt, 3, kn1);
    __builtin_amdgcn_s_barrier();
    asm volatile("s_waitcnt lgkmcnt(0)" ::: "memory");
    __builtin_amdgcn_sched_barrier(0);          // rule 18: pin MFMA below wait
    __builtin_amdgcn_s_setprio(1);
#pragma unroll
    for (int ks = 0; ks < 2; ++ks)
#pragma unroll
      for (int mi = 0; mi < 4; ++mi)
#pragma unroll
        for (int ni = 0; ni < 2; ++ni)
          acc[mi][ni] = __builtin_amdgcn_mfma_f32_16x16x32_bf16(a0[mi][ks], b0[ni][ks], acc[mi][ni], 0, 0, 0);
    __builtin_amdgcn_s_setprio(0);
    __builtin_amdgcn_s_barrier();

    // ---- phase 1: quad (m0,n1). ds_read B-h1.
    //      stage A0,A2 of tile kt+2 -> cur (freed by ph0 end barrier).
#pragma unroll
    for (int ni = 0; ni < 2; ++ni) {
      const int r = wn * 64 + 32 + ni * 16 + lm;
#pragma unroll
      for (int ks = 0; ks < 2; ++ks) b1[ni][ks] = LD_B(cur, r, ks * 4 + lq);
    }
    STAGE_A(cur, 0, kn2); STAGE_A(cur, 2, kn2);
    __builtin_amdgcn_s_barrier();
    asm volatile("s_waitcnt lgkmcnt(0)" ::: "memory");
    __builtin_amdgcn_sched_barrier(0);
    __builtin_amdgcn_s_setprio(1);
#pragma unroll
    for (int ks = 0; ks < 2; ++ks)
#pragma unroll
      for (int mi = 0; mi < 4; ++mi)
#pragma unroll
        for (int ni = 0; ni < 2; ++ni)
          acc[mi][2 + ni] = __builtin_amdgcn_mfma_f32_16x16x32_bf16(a0[mi][ks], b1[ni][ks], acc[mi][2 + ni], 0, 0, 0);
    __builtin_amdgcn_s_setprio(0);
    // deep counted wait: drains [kt-1 ph0] (A1,A3 of tile kt, needed by ph2's
    // ds_read) — issued 5 phases ago. Queue holds 12 -> leave 10 in flight.
    asm volatile("s_waitcnt vmcnt(10)" ::: "memory");
    __builtin_amdgcn_sched_barrier(0);
    __builtin_amdgcn_s_barrier();

    // ---- phase 2: quad (m1,n0). ds_read A-h1 (slots 1,3).
    //      stage B0,B1 of tile kt+2 -> cur (freed by ph1 end barrier).
#pragma unroll
    for (int mi = 0; mi < 4; ++mi) {
      const int r = wm * 128 + 64 + mi * 16 + lm;
#pragma unroll
      for (int ks = 0; ks < 2; ++ks) a1[mi][ks] = LD_A(cur, r, ks * 4 + lq);
    }
    STAGE_B(cur, 0, kn2); STAGE_B(cur, 1, kn2);
    __builtin_amdgcn_s_barrier();
    asm volatile("s_waitcnt lgkmcnt(0)" ::: "memory");
    __builtin_amdgcn_sched_barrier(0);
    __builtin_amdgcn_s_setprio(1);
#pragma unroll
    for (int ks = 0; ks < 2; ++ks)
#pragma unroll
      for (int mi = 0; mi < 4; ++mi)
#pragma unroll
        for (int ni = 0; ni < 2; ++ni)
          acc[4 + mi][ni] = __builtin_amdgcn_mfma_f32_16x16x32_bf16(a1[mi][ks], b0[ni][ks], acc[4 + mi][ni], 0, 0, 0);
    __builtin_amdgcn_s_setprio(0);
    __builtin_amdgcn_s_barrier();

    // ---- phase 3: quad (m1,n1) — no ds_read (operands from ph1/ph2).
    //      stage B2,B3 of tile kt+2 -> cur (freed since ph1 end barrier).
    STAGE_B(cur, 2, kn2); STAGE_B(cur, 3, kn2);
    __builtin_amdgcn_s_setprio(1);
#pragma unroll
    for (int ks = 0; ks < 2; ++ks)
#pragma unroll
      for (int mi = 0; mi < 4; ++mi)
#pragma unroll
        for (int ni = 0; ni < 2; ++ni)
          acc[4 + mi][2 + ni] = __builtin_amdgcn_mfma_f32_16x16x32_bf16(a1[mi][ks], b1[ni][ks], acc[4 + mi][2 + ni], 0, 0, 0);
    __builtin_amdgcn_s_setprio(0);
    // deep counted wait: drains [kt-1 ph1..ph3] (tile kt+1's A0,A2,B0..B3,
    // needed by next iter ph0) — issued 4-6 phases ago. Leave 8 in flight.
    asm volatile("s_waitcnt vmcnt(8)" ::: "memory");
    __builtin_amdgcn_sched_barrier(0);
    __builtin_amdgcn_s_barrier();   // publishes tile kt+1's LDS for phase 0
  }

  // epilogue: C/D layout col=lane&15, row=(lane>>4)*4+reg
#pragma unroll
  for (int nj = 0; nj < 4; ++nj) {
    const long col = col0 + wn * 64 + nj * 16 + lm;
    float bv;
    if (MODE == 5)
      bv = (col < 2048) ? bias0[col] : (col < 4096 ? bias1[col - 2048] : bias2[col - 4096]);
    else if (MODE == 6)
      bv = (col < 2048) ? bias0[col] : bias1[col - 2048];
    else
      bv = bias0[col];
#pragma unroll
    for (int fi = 0; fi < 8; ++fi) {
#pragma unroll
      for (int r = 0; r < 4; ++r) {
        const long row = row0 + wm * 128 + fi * 16 + lq * 4 + r;
        ((bf16*)Cout)[row * ldC + col] = (bf16)(acc[fi][nj][r] + bv);
      }
    }
  }
#undef STAGE_A
#undef STAGE_B
#undef LD_A
#undef LD_B
}

// ============================================================================
// old 128x128 GEMM — kept for the O-projection (M=4096,N=2048: at 256^2 tiles
// the grid would be 128 blocks = half the GPU idle). MODE 1 only:
// f32 out = resid + acc + bias0 (in-place on resid allowed)
// ============================================================================
template<int MODE>
__global__ __launch_bounds__(256)
void gemm_bt(const bf16* __restrict__ A, int ldA,
             const bf16* __restrict__ Bw, int K,
             const float* __restrict__ bias0,
             void* Cout, int ldC,
             const float* resid)
{
  __shared__ bf16 sA[128 * 32];
  __shared__ bf16 sB[128 * 32];
  const int tid  = threadIdx.x;
  const int lane = tid & 63;
  const int wave = tid >> 6;
  const int wm = wave >> 1, wn = wave & 1;
  const long row0 = (long)blockIdx.y * 128;
  const long col0 = (long)blockIdx.x * 128;

  const bf16* Ab = A  + row0 * ldA;
  const bf16* Bb = Bw + col0 * (long)K;

  f32x4 acc[4][4] = {};

  const int c0 = tid,        c1 = tid + 256;
  const int r0 = c0 >> 2,    cc0 = (c0 & 3) * 8;
  const int r1 = c1 >> 2,    cc1 = (c1 & 3) * 8;

  for (int k0 = 0; k0 < K; k0 += 32) {
    g2l16(Ab + (long)r0 * ldA + k0 + cc0, sA + c0 * 8);
    g2l16(Ab + (long)r1 * ldA + k0 + cc1, sA + c1 * 8);
    g2l16(Bb + (long)r0 * K   + k0 + cc0, sB + c0 * 8);
    g2l16(Bb + (long)r1 * K   + k0 + cc1, sB + c1 * 8);
    __syncthreads();
    const int lm = lane & 15, lq = lane >> 4;
    bf16x8 af[4], bfr[4];
#pragma unroll
    for (int mi = 0; mi < 4; ++mi)
      af[mi] = *(const bf16x8*)(sA + (wm * 64 + mi * 16 + lm) * 32 + lq * 8);
#pragma unroll
    for (int ni = 0; ni < 4; ++ni)
      bfr[ni] = *(const bf16x8*)(sB + (wn * 64 + ni * 16 + lm) * 32 + lq * 8);
#pragma unroll
    for (int mi = 0; mi < 4; ++mi)
#pragma unroll
      for (int ni = 0; ni < 4; ++ni)
        acc[mi][ni] = __builtin_amdgcn_mfma_f32_16x16x32_bf16(af[mi], bfr[ni], acc[mi][ni], 0, 0, 0);
    __syncthreads();
  }

  const int lm = lane & 15, lq = lane >> 4;
#pragma unroll
  for (int ni = 0; ni < 4; ++ni) {
    const long col = col0 + wn * 64 + ni * 16 + lm;
    const float bv = bias0[col];
#pragma unroll
    for (int mi = 0; mi < 4; ++mi) {
#pragma unroll
      for (int r = 0; r < 4; ++r) {
        const long row = row0 + wm * 64 + mi * 16 + lq * 4 + r;
        const long idx = row * ldC + col;
        ((float*)Cout)[idx] = resid[idx] + acc[mi][ni][r] + bv;
      }
    }
  }
}

// ============================================================================
// fused (optional additive-rotary) + RMSNorm
// ============================================================================
__global__ __launch_bounds__(256)
void rms_rot(const float* __restrict__ xin,
             const float* __restrict__ scale,
             float* __restrict__ xr_out,
             bf16* __restrict__ h_out,
             int do_rot)
{
  const int row = blockIdx.x, tid = threadIdx.x;
  const float s = (float)(row & (SEQ - 1));
  const float4* xrow = (const float4*)(xin + (long)row * DIMM);
  float4 v[2];
  float ss = 0.f;
#pragma unroll
  for (int i = 0; i < 2; ++i) {
    const int j4 = tid + i * 256;
    float4 xv = xrow[j4];
    if (do_rot) {
      float* xp = (float*)&xv;
#pragma unroll
      for (int l = 0; l < 4; ++l) {
        const int idx = (j4 * 4 + l) & 1023;
        xp[l] += s * exp2f((float)idx * -0.0129762816206537569f);
      }
    }
    v[i] = xv;
    ss += xv.x * xv.x + xv.y * xv.y + xv.z * xv.z + xv.w * xv.w;
    if (xr_out) ((float4*)(xr_out + (long)row * DIMM))[j4] = xv;
  }
#pragma unroll
  for (int off = 32; off > 0; off >>= 1) ss += __shfl_down(ss, off, 64);
  __shared__ float red[4];
  if ((tid & 63) == 0) red[tid >> 6] = ss;
  __syncthreads();
  const float rn = rsqrtf(red[0] + red[1] + red[2] + red[3] + EPSF);
  bf16* hrow = h_out + (long)row * DIMM;
#pragma unroll
  for (int i = 0; i < 2; ++i) {
    const int j4 = tid + i * 256;
    const float4 xv = v[i];
    const float4 s4 = ((const float4*)scale)[j4];
    bf16x4 o;
    o[0] = (bf16)(s4.x * xv.x * rn);
    o[1] = (bf16)(s4.y * xv.y * rn);
    o[2] = (bf16)(s4.z * xv.z * rn);
    o[3] = (bf16)(s4.w * xv.w * rn);
    *(bf16x4*)(hrow + j4 * 4) = o;
  }
}

// ============================================================================
// per-position attention over HEADS
// ============================================================================
__global__ __launch_bounds__(256)
void attn_kernel(const bf16* QKV, bf16* CTX)
{
  __shared__ float qs[32 * 68];
  __shared__ float ks[32 * 68];
  __shared__ float vs[2048];
  __shared__ float sc[32 * 33];
  const int p = blockIdx.x, tid = threadIdx.x;
  const bf16* base = QKV + (long)p * 6144;
  {
    const bf16x8 q8 = *(const bf16x8*)(base + tid * 8);
    const bf16x8 k8 = *(const bf16x8*)(base + 2048 + tid * 8);
    const bf16x8 v8 = *(const bf16x8*)(base + 4096 + tid * 8);
    const int hi = tid >> 3, d0 = (tid & 7) * 8;
#pragma unroll
    for (int l = 0; l < 8; ++l) {
      qs[hi * 68 + d0 + l] = (float)q8[l];
      ks[hi * 68 + d0 + l] = (float)k8[l];
      vs[hi * 64 + d0 + l] = (float)v8[l];
    }
  }
  __syncthreads();
  {
    const int qi = tid >> 3, ku = tid & 7;
    float a[4] = {0.f, 0.f, 0.f, 0.f};
#pragma unroll
    for (int d = 0; d < 64; d += 4) {
      const float4 qv = *(const float4*)&qs[qi * 68 + d];
#pragma unroll
      for (int c = 0; c < 4; ++c) {
        const float4 kv = *(const float4*)&ks[(ku + 8 * c) * 68 + d];
        a[c] += qv.x * kv.x + qv.y * kv.y + qv.z * kv.z + qv.w * kv.w;
      }
    }
#pragma unroll
    for (int c = 0; c < 4; ++c) sc[qi * 33 + ku + 8 * c] = a[c] * 0.125f;
  }
  __syncthreads();
  if (tid < 32) {
    float mx = -1e30f;
#pragma unroll
    for (int k = 0; k < 32; ++k) mx = fmaxf(mx, sc[tid * 33 + k]);
    float e[32], sum = 0.f;
#pragma unroll
    for (int k = 0; k < 32; ++k) { e[k] = __expf(sc[tid * 33 + k] - mx); sum += e[k]; }
    const float inv = 1.f / sum;
#pragma unroll
    for (int k = 0; k < 32; ++k) sc[tid * 33 + k] = e[k] * inv;
  }
  __syncthreads();
  {
    const int q = tid >> 3, d0 = (tid & 7) * 8;
    float a[8] = {};
#pragma unroll
    for (int k = 0; k < 32; ++k) {
      const float w = sc[q * 33 + k];
      const float4 v0 = *(const float4*)&vs[k * 64 + d0];
      const float4 v1 = *(const float4*)&vs[k * 64 + d0 + 4];
      a[0] += w * v0.x; a[1] += w * v0.y; a[2] += w * v0.z; a[3] += w * v0.w;
      a[4] += w * v1.x; a[5] += w * v1.y; a[6] += w * v1.z; a[7] += w * v1.w;
    }
    bf16x8 o;
#pragma unroll
    for (int l = 0; l < 8; ++l) o[l] = (bf16)a[l];
    *(bf16x8*)(CTX + (long)p * 6144 + tid * 8) = o;
  }
}

// ============================================================================
// swiglu combine
// ============================================================================
__global__ __launch_bounds__(256)
void swiglu_combine(const bf16* __restrict__ G12, const float* __restrict__ R,
                    float* __restrict__ out)
{
  const long idx = ((long)blockIdx.x * 256 + threadIdx.x) * 8;
  const long row = idx >> 11, col = idx & 2047;
  const bf16x8 g1 = *(const bf16x8*)(G12 + row * 4096 + col);
  const bf16x8 g2 = *(const bf16x8*)(G12 + row * 4096 + 2048 + col);
  const float4 r0 = *(const float4*)(R + idx);
  const float4 r1 = *(const float4*)(R + idx + 4);
  float o[8];
  const float* rp0 = (const float*)&r0;
  const float* rp1 = (const float*)&r1;
#pragma unroll
  for (int l = 0; l < 8; ++l) {
    const float g  = (float)g1[l];
    const float si = g / (1.f + __expf(-g));
    const float rv = l < 4 ? rp0[l] : rp1[l - 4];
    o[l] = rv + si * (float)g2[l];
  }
  *(float4*)(out + idx)     = make_float4(o[0], o[1], o[2], o[3]);
  *(float4*)(out + idx + 4) = make_float4(o[4], o[5], o[6], o[7]);
}

// ============================================================================
// fp32 -> bf16 weight pool
// ============================================================================
__global__ __launch_bounds__(256)
void convert_weights(const float* __restrict__ wq, const float* __restrict__ wk,
                     const float* __restrict__ wv, const float* __restrict__ wo,
                     const float* __restrict__ w_in, const float* __restrict__ w1,
                     const float* __restrict__ w2, bf16* __restrict__ dst)
{
  const long i = ((long)blockIdx.x * 256 + threadIdx.x) * 4;
  const float* src; long loc;
  if (i < (1L << 24)) {
    const long seg = i >> 22;
    src = seg == 0 ? wq : seg == 1 ? wk : seg == 2 ? wv : wo;
    loc = i & ((1L << 22) - 1);
  } else {
    const long j = i - (1L << 24);
    const long seg = j >> 24;
    src = seg == 0 ? w_in : seg == 1 ? w1 : w2;
    loc = j & ((1L << 24) - 1);
  }
  const float4 f = *(const float4*)(src + loc);
  bf16x4 o;
  o[0] = (bf16)f.x; o[1] = (bf16)f.y; o[2] = (bf16)f.z; o[3] = (bf16)f.w;
  *(bf16x4*)(dst + i) = o;
}

extern "C" void kernel_launch(void* const* d_in, const int* in_sizes, int n_in,
                              void* d_out, int out_size, void* d_ws, size_t ws_size,
                              hipStream_t stream)
{
  const float* x      = (const float*)d_in[0];
  const float* wq     = (const float*)d_in[1];
  const float* bq     = (const float*)d_in[2];
  const float* wk     = (const float*)d_in[3];
  const float* bk     = (const float*)d_in[4];
  const float* wv     = (const float*)d_in[5];
  const float* bv     = (const float*)d_in[6];
  const float* wo     = (const float*)d_in[7];
  const float* bo     = (const float*)d_in[8];
  const float* scale1 = (const float*)d_in[9];
  const float* scale2 = (const float*)d_in[10];
  const float* w_in   = (const float*)d_in[11];
  const float* b_in   = (const float*)d_in[12];
  const float* w1     = (const float*)d_in[13];
  const float* b1     = (const float*)d_in[14];
  const float* w2     = (const float*)d_in[15];
  const float* b2     = (const float*)d_in[16];

  char* ws = (char*)d_ws;
  bf16*  WB  = (bf16*)ws;                      // 134217728 B: bf16 weight pool
  float* R   = (float*)(ws + 134217728);       //  33554432 B: fp32 residual
  bf16*  H   = (bf16*) (ws + 167772160);       //  16777216 B: bf16 normed acts
  bf16*  QKV = (bf16*) (ws + 184549376);       //  48 MB region (phase 1)
  bf16*  HID = (bf16*) (ws + 184549376);       //  64 MB region (phase 2, aliases QKV)
  bf16*  G12 = (bf16*) (ws + 251658240);       //  33554432 B: bf16 [4096,4096] g1|g2
  if (ws_size < 285212672ULL) { fprintf(stderr, "ws too small: %zu\n", ws_size); return; }

  bf16* wqkv_b = WB;
  bf16* wo_b   = WB + 12582912;
  bf16* win_b  = WB + 16777216;
  bf16* w12_b  = WB + 33554432;

  convert_weights<<<65536, 256, 0, stream>>>(wq, wk, wv, wo, w_in, w1, w2, WB);
  // xr = x + rotary ; h1 = rmsnorm(xr, scale1)
  rms_rot<<<ROWS, 256, 0, stream>>>(x, scale1, R, H, 1);
  // fused QKV: [4096,6144]  (256^2 tiles: 24 x 16 = 384 blocks)
  gemm256<5><<<dim3(24, 16), 512, 0, stream>>>(H, 2048, wqkv_b, 2048, bq, bk, bv,
                                               QKV, 6144);
  // per-position head attention; ctx -> Q slot of QKV
  attn_kernel<<<ROWS, 256, 0, stream>>>(QKV, QKV);
  // x2 = xr + ctx @ wo^T + bo   (in-place on R) — small GEMM, keep 128^2 grid
  gemm_bt<1><<<dim3(16, 32), 256, 0, stream>>>(QKV, 6144, wo_b, 2048, bo, R, 2048, R);
  // h2 = rmsnorm(x2, scale2) -> H
  rms_rot<<<ROWS, 256, 0, stream>>>(R, scale2, nullptr, H, 0);
  // hidden = h2 @ w_in^T + b_in  [4096,8192]  (32 x 16 = 512 blocks)
  gemm256<0><<<dim3(32, 16), 512, 0, stream>>>(H, 2048, win_b, 2048, b_in, nullptr, nullptr,
                                               HID, 8192);
  // fused g1|g2 = hidden @ [w1|w2]^T + [b1|b2]  (16 x 16 = 256 blocks)
  gemm256<6><<<dim3(16, 16), 512, 0, stream>>>(HID, 8192, w12_b, 8192, b1, b2, nullptr,
                                               G12, 4096);
  // out = x2 + silu(g1) * g2
  swiglu_combine<<<4096, 256, 0, stream>>>(G12, R, (float*)d_out);
}